// Round 2
// baseline (105.447 us; speedup 1.0000x reference)
//
#include <hip/hip_runtime.h>

// Problem constants (from setup_inputs): bs=8, L=256, C=32, OUT=32, H=16, s=5, K=5
#define BS   8
#define LEN  256
#define CCH  32          // C
#define OUTC 32          // OUT
#define HID  16          // H
#define SS   5           // sim_size
#define KK   5           // KERNEL_SIZE
#define LALL ((SS + 1) * LEN - SS)   // 1531
#define MPB  8           // Q rows per block in build_q

// ---------------------------------------------------------------------------
// Kernel A: Q[b*L + m, h*32 + o] = sum_c tf[b,m,c] * W2[h, c*32 + o]
// One block handles MPB consecutive rows m, so W2 (64 KB) is read once/block.
// ---------------------------------------------------------------------------
__global__ __launch_bounds__(256) void build_q_kernel(
        const float* __restrict__ tf, const float* __restrict__ W2,
        float* __restrict__ Q) {
    const int blk = blockIdx.x;           // covers bm = blk*MPB .. +MPB-1
    const int tid = threadIdx.x;
    __shared__ float sF[MPB][CCH];
    for (int e = tid; e < MPB * CCH; e += 256) {
        int r = e >> 5, c = e & 31;
        sF[r][c] = tf[(size_t)(blk * MPB + r) * CCH + c];
    }
    __syncthreads();
    for (int e = tid; e < HID * OUTC; e += 256) {   // 512 entries, 2 per thread
        int h = e >> 5, o = e & 31;
        float acc[MPB];
#pragma unroll
        for (int r = 0; r < MPB; ++r) acc[r] = 0.f;
        const float* w = W2 + (size_t)h * (CCH * OUTC) + o;
#pragma unroll
        for (int c = 0; c < CCH; ++c) {
            float wv = w[c * OUTC];
#pragma unroll
            for (int r = 0; r < MPB; ++r) acc[r] += sF[r][c] * wv;
        }
#pragma unroll
        for (int r = 0; r < MPB; ++r)
            Q[(size_t)(blk * MPB + r) * (HID * OUTC) + e] = acc[r];
    }
}

// ---------------------------------------------------------------------------
// Kernel B: one block per (b, l).  Covers sim points j in [6l, 6l+6) ∩ [0,1531).
//   pcf/pct index l1 = j//6 == l for all 6 j's; dm indexes (j+5)//6:
//   jr==0 -> dm at l, jr>=1 -> dm at l+1.
// out[b,j,o] = sum_k dm * ( sum_h h[jr,k,h]*P2[k,h,o] + Pb[k,o] )
//   P2[k] = Q[b, l+k-4] (zero for l+k<4);  Pb[k,o] = sum_c F[k,c]*b2[c*32+o]
//   h = relu( te @ W1 + b1 ),  te[c] = sin/cos((times[b,j]-pct[k]) / pos[c])
// ---------------------------------------------------------------------------
__global__ __launch_bounds__(256) void main_kernel(
        const float* __restrict__ times, const float* __restrict__ true_times,
        const float* __restrict__ tf,    const int* __restrict__ mask,
        const float* __restrict__ W1,    const float* __restrict__ b1,
        const float* __restrict__ W2,    const float* __restrict__ b2,
        const float* __restrict__ Q,     int use_q,
        float* __restrict__ out) {
    const int l = blockIdx.x;     // 0..255
    const int b = blockIdx.y;     // 0..7
    const int tid = threadIdx.x;

    __shared__ float sA[KK * HID * OUTC];   // P2: 2560
    __shared__ float sPb[KK * OUTC];        // 160
    __shared__ float sF[KK * CCH];          // 160
    __shared__ float sW1[CCH * HID];        // 512
    __shared__ float sb1[HID];
    __shared__ float sPT[KK];
    __shared__ float sDM[KK][2];
    __shared__ float sT[6];
    __shared__ float sInv[16];              // 1/pos for c>>1
    __shared__ float sTE[6 * KK * CCH];     // 960
    __shared__ float sH[6 * KK * HID];      // 480

    // ---- phase 1: small loads ----
    for (int e = tid; e < CCH * HID; e += 256) sW1[e] = W1[e];  // 512 > blockDim!
    if (tid < HID) sb1[tid] = b1[tid];
    if (tid < 16) sInv[tid] = __powf(10000.f, -(float)tid * (1.f / 16.f));
    if (tid < KK * CCH) {
        int k = tid >> 5, c = tid & 31;
        int row = l + k - (KK - 1);
        sF[tid] = (row >= 0) ? tf[(size_t)(b * LEN + row) * CCH + c] : 0.f;
    }
    if (tid < KK) {
        int row = l + tid - (KK - 1);
        sPT[tid] = (row >= 0) ? true_times[b * LEN + row] : 0.f;
    }
    if (tid >= 32 && tid < 32 + 2 * KK) {
        int t = tid - 32;
        int k = t >> 1, sel = t & 1;
        int lm = l + sel; if (lm > LEN - 1) lm = LEN - 1;   // sel=1 unused at l=255
        int row = lm + k - (KK - 1);
        bool v = (row >= 0) && (mask[b * LEN + row] != 0) && (mask[b * LEN + lm] != 0);
        sDM[k][sel] = v ? 1.f : 0.f;
    }
    if (tid >= 64 && tid < 64 + 6) {
        int jr = tid - 64;
        int j = 6 * l + jr;
        sT[jr] = (j < LALL) ? times[(size_t)b * LALL + j] : 0.f;
    }
    __syncthreads();

    // ---- phase 2: P2 (from Q, or recomputed from W2) + Pb ----
    if (use_q) {
        for (int e = tid; e < KK * HID * OUTC; e += 256) {
            int k = e >> 9, rem = e & 511;
            int row = l + k - (KK - 1);
            sA[e] = (row >= 0) ? Q[(size_t)(b * LEN + row) * (HID * OUTC) + rem] : 0.f;
        }
    } else {
        for (int e = tid; e < KK * HID * OUTC; e += 256) {
            int k = e >> 9, rem = e & 511;
            int h = rem >> 5, o = rem & 31;
            float acc = 0.f;
            const float* w = W2 + (size_t)h * (CCH * OUTC) + o;
#pragma unroll
            for (int c = 0; c < CCH; ++c) acc += sF[k * CCH + c] * w[c * OUTC];
            sA[e] = acc;
        }
    }
    if (tid < KK * OUTC) {
        int k = tid >> 5, o = tid & 31;
        float acc = 0.f;
#pragma unroll
        for (int c = 0; c < CCH; ++c) acc += sF[k * CCH + c] * b2[c * OUTC + o];
        sPb[tid] = acc;
    }

    // ---- phase 3a: temporal encoding te[jr,k,c]  (960 values) ----
    for (int e = tid; e < 6 * KK * CCH; e += 256) {
        int jr = e / 160;
        int rem = e - jr * 160;
        int k = rem >> 5, c = rem & 31;
        float dt = sT[jr] - sPT[k];
        float r = dt * sInv[c >> 1];
        sTE[e] = (c & 1) ? __cosf(r) : __sinf(r);
    }
    __syncthreads();   // sA, sPb, sTE all ready

    // ---- phase 3b: h[jr,k,hh] = relu(te @ W1 + b1)  (480 values) ----
    for (int e = tid; e < 6 * KK * HID; e += 256) {
        int jr = e / 80;
        int rem = e - jr * 80;
        int k = rem >> 4, hh = rem & 15;
        float acc = sb1[hh];
        const float* te = &sTE[jr * 160 + k * 32];
#pragma unroll
        for (int c = 0; c < CCH; ++c) acc += te[c] * sW1[c * HID + hh];
        sH[e] = acc > 0.f ? acc : 0.f;
    }
    __syncthreads();

    // ---- phase 4: out[b, 6l+jr, o] ----
    if (tid < 6 * OUTC) {
        int jr = tid >> 5, o = tid & 31;
        int j = 6 * l + jr;
        if (j < LALL) {
            float acc = 0.f;
#pragma unroll
            for (int k = 0; k < KK; ++k) {
                float dmv = sDM[k][jr > 0 ? 1 : 0];
                float a2 = sPb[k * OUTC + o];
                const float* hp = &sH[jr * 80 + k * 16];
                const float* ap = &sA[k * 512 + o];
#pragma unroll
                for (int hh = 0; hh < HID; ++hh) a2 += hp[hh] * ap[hh * 32];
                acc += dmv * a2;
            }
            out[((size_t)b * LALL + j) * OUTC + o] = acc;
        }
    }
}

extern "C" void kernel_launch(void* const* d_in, const int* in_sizes, int n_in,
                              void* d_out, int out_size, void* d_ws, size_t ws_size,
                              hipStream_t stream) {
    const float* times      = (const float*)d_in[0];
    const float* true_times = (const float*)d_in[1];
    const float* tf         = (const float*)d_in[2];
    const int*   mask       = (const int*)d_in[3];
    // d_in[4] = sim_size (scalar, =5, baked into constants)
    const float* W1         = (const float*)d_in[5];
    const float* b1         = (const float*)d_in[6];
    const float* W2         = (const float*)d_in[7];
    const float* b2         = (const float*)d_in[8];
    float* out = (float*)d_out;

    const size_t qbytes = (size_t)BS * LEN * HID * OUTC * sizeof(float); // 4 MB
    const int use_q = (ws_size >= qbytes) ? 1 : 0;
    float* Q = (float*)d_ws;

    if (use_q) {
        build_q_kernel<<<dim3(BS * LEN / MPB), 256, 0, stream>>>(tf, W2, Q);
    }
    main_kernel<<<dim3(LEN, BS), 256, 0, stream>>>(
        times, true_times, tf, mask, W1, b1, W2, b2, Q, use_q, out);
}

// Round 3
// 82.752 us; speedup vs baseline: 1.2742x; 1.2742x over previous
//
#include <hip/hip_runtime.h>

// Problem constants (from setup_inputs): bs=8, L=256, C=32, OUT=32, H=16, s=5, K=5
#define BS   8
#define LEN  256
#define CCH  32          // C
#define OUTC 32          // OUT
#define HID  16          // H
#define SS   5           // sim_size
#define KK   5           // KERNEL_SIZE
#define LALL ((SS + 1) * LEN - SS)   // 1531
#define LPB  4           // l-values per block (windows overlap: LPB+4 rows)
#define NROW (LPB + KK - 1)          // 8 source rows per block
#define NCH  (LPB * 6 * KK)          // 120 (jl,k) chunks for TE/H
#define TES  33                      // padded TE chunk stride (bank-conflict free)

// One fused kernel. Block = (b, l-group of 4). For each l in group, sim points
// j in [6l, 6l+6): pcf/pct index l (=j//6), dm indexes (j+5)//6 (jr==0 -> l,
// jr>=1 -> l+1). dm in {0,1} multiplies both pcf and kv in the reference, so a
// single output-side factor is exact.
//   out[b,j,o] = sum_k dm * ( sum_h h[jl,k,h]*Q[row,h,o] + Pb[row,o] )
//   row = l+k-4 (ri = il+k in the block's row window)
//   Q[row] = F[row,:] @ W2  (16x32 per row), Pb[row] = F[row,:] @ b2
//   h = relu(te @ W1 + b1), te[c] = sin/cos((times[b,j]-tt[row]) * inv_pos[c/2])
__global__ __launch_bounds__(256) void fused_kernel(
        const float* __restrict__ times, const float* __restrict__ true_times,
        const float* __restrict__ tf,    const int* __restrict__ mask,
        const float* __restrict__ W1,    const float* __restrict__ b1,
        const float* __restrict__ W2,    const float* __restrict__ b2,
        float* __restrict__ out) {
    const int l0  = blockIdx.x * LPB;   // first l of this block
    const int b   = blockIdx.y;
    const int tid = threadIdx.x;

    __shared__ float sQ[NROW][HID * OUTC];      // 8*512   = 16 KB
    __shared__ float sPb[NROW][OUTC];           // 8*32
    __shared__ float sF[NROW][CCH];             // 8*32
    __shared__ float sW1[CCH * HID];            // 512
    __shared__ float sb1[HID];
    __shared__ float sPT[NROW];                 // true_times per row
    __shared__ float sM[NROW + 1];              // mask rows l0-4 .. l0+LPB
    __shared__ float sT[LPB * 6];               // times for the 24 sim points
    __shared__ float sInv[16];                  // 1/pos per (c>>1)
    __shared__ float sTE[NCH * TES];            // 120*33 = 15.5 KB
    __shared__ float sH[NCH * HID];             // 1920   = 7.5 KB

    // ---- phase 1: small loads ----
    for (int e = tid; e < CCH * HID; e += 256) sW1[e] = W1[e];
    if (tid < HID) sb1[tid] = b1[tid];
    if (tid < 16) sInv[tid] = __powf(10000.f, -(float)tid * (1.f / 16.f));
    if (tid < NROW * CCH) {                     // 256 exactly
        int ri = tid >> 5, c = tid & 31;
        int row = l0 + ri - (KK - 1);
        sF[ri][c] = (row >= 0) ? tf[(size_t)(b * LEN + row) * CCH + c] : 0.f;
    }
    if (tid < NROW) {
        int row = l0 + tid - (KK - 1);
        sPT[tid] = (row >= 0) ? true_times[b * LEN + row] : 0.f;
    }
    if (tid >= 32 && tid < 32 + NROW + 1) {
        int i = tid - 32;
        int row = l0 + i - (KK - 1);
        int rc = row < (LEN - 1) ? row : (LEN - 1);   // i==NROW only when l0+LPB==LEN (unused)
        sM[i] = (row >= 0 && mask[b * LEN + rc] != 0) ? 1.f : 0.f;
    }
    if (tid >= 64 && tid < 64 + LPB * 6) {
        int jl = tid - 64;
        int j = 6 * l0 + jl;
        sT[jl] = (j < LALL) ? times[(size_t)b * LALL + j] : 0.f;
    }
    __syncthreads();

    // ---- phase 2a: Q rows (F @ W2), 2 (h,o) columns per thread, all 8 rows ----
    {
        int o = tid & 31;
        int h0 = tid >> 5;            // rem0 = tid       -> h = tid>>5
        int h1 = (tid + 256) >> 5;    // rem1 = tid + 256
        const float* w0 = W2 + (size_t)h0 * (CCH * OUTC) + o;
        const float* w1 = W2 + (size_t)h1 * (CCH * OUTC) + o;
        float acc0[NROW], acc1[NROW];
#pragma unroll
        for (int r = 0; r < NROW; ++r) { acc0[r] = 0.f; acc1[r] = 0.f; }
#pragma unroll
        for (int c = 0; c < CCH; ++c) {
            float wv0 = w0[c * OUTC];
            float wv1 = w1[c * OUTC];
#pragma unroll
            for (int r = 0; r < NROW; ++r) {
                float fv = sF[r][c];            // same addr across lanes: broadcast
                acc0[r] += fv * wv0;
                acc1[r] += fv * wv1;
            }
        }
#pragma unroll
        for (int r = 0; r < NROW; ++r) {
            sQ[r][tid]       = acc0[r];
            sQ[r][tid + 256] = acc1[r];
        }
    }
    // ---- phase 2b: Pb rows (F @ b2) ----
    {
        int ri = tid >> 5, o = tid & 31;      // 256 = NROW*32 exactly
        float acc = 0.f;
#pragma unroll
        for (int c = 0; c < CCH; ++c) acc += sF[ri][c] * b2[c * OUTC + o];
        sPb[ri][o] = acc;
    }
    // ---- phase 2c: temporal encoding te (3840 values, 15/thread) ----
    for (int e = tid; e < NCH * CCH; e += 256) {
        int c  = e & 31;
        int k  = (e >> 5) % KK;
        int jl = e / (KK * CCH);              // il*6 + jr
        int il = jl / 6;
        float dt = sT[jl] - sPT[il + k];
        float r = dt * sInv[c >> 1];
        sTE[(jl * KK + k) * TES + c] = (c & 1) ? __cosf(r) : __sinf(r);
    }
    __syncthreads();

    // ---- phase 3: h = relu(te @ W1 + b1)  (1920 values) ----
    for (int e = tid; e < NCH * HID; e += 256) {
        int hh = e & 15;
        int ch = e >> 4;                      // chunk = jl*5 + k, 0..119
        const float* te = &sTE[ch * TES];
        float acc = sb1[hh];
#pragma unroll
        for (int c = 0; c < CCH; ++c) acc += te[c] * sW1[c * HID + hh];
        sH[ch * HID + hh] = acc > 0.f ? acc : 0.f;
    }
    __syncthreads();

    // ---- phase 4: outputs (768 values, 3/thread) ----
    for (int e = tid; e < LPB * 6 * OUTC; e += 256) {
        int o  = e & 31;
        int jr = (e >> 5) % 6;
        int il = e / (6 * OUTC);
        int j = 6 * (l0 + il) + jr;
        if (j < LALL) {
            int sel = jr > 0 ? 1 : 0;
            float mlm = sM[il + sel + (KK - 1)];
            float acc = 0.f;
#pragma unroll
            for (int k = 0; k < KK; ++k) {
                float dmv = sM[il + sel + k] * mlm;
                int ri = il + k;
                const float* hp = &sH[((il * 6 + jr) * KK + k) * HID];
                const float* qp = &sQ[ri][o];
                float a2 = sPb[ri][o];
#pragma unroll
                for (int hh = 0; hh < HID; ++hh) a2 += hp[hh] * qp[hh * OUTC];
                acc += dmv * a2;
            }
            out[((size_t)b * LALL + j) * OUTC + o] = acc;
        }
    }
}

extern "C" void kernel_launch(void* const* d_in, const int* in_sizes, int n_in,
                              void* d_out, int out_size, void* d_ws, size_t ws_size,
                              hipStream_t stream) {
    const float* times      = (const float*)d_in[0];
    const float* true_times = (const float*)d_in[1];
    const float* tf         = (const float*)d_in[2];
    const int*   mask       = (const int*)d_in[3];
    // d_in[4] = sim_size (scalar, =5, baked into constants)
    const float* W1         = (const float*)d_in[5];
    const float* b1         = (const float*)d_in[6];
    const float* W2         = (const float*)d_in[7];
    const float* b2         = (const float*)d_in[8];
    float* out = (float*)d_out;

    fused_kernel<<<dim3(LEN / LPB, BS), 256, 0, stream>>>(
        times, true_times, tf, mask, W1, b1, W2, b2, out);
}

// Round 4
// 81.620 us; speedup vs baseline: 1.2919x; 1.0139x over previous
//
#include <hip/hip_runtime.h>

// Problem constants (from setup_inputs): bs=8, L=256, C=32, OUT=32, H=16, s=5, K=5
#define BS   8
#define LEN  256
#define CCH  32          // C
#define OUTC 32          // OUT
#define HID  16          // H
#define SS   5           // sim_size
#define KK   5           // KERNEL_SIZE
#define LALL ((SS + 1) * LEN - SS)   // 1531
#define LPB  8           // l-values per block (windows overlap: LPB+4 rows)
#define NROW (LPB + KK - 1)          // 12 source rows per block
#define NCH  (LPB * 6 * KK)          // 240 (jl,k) chunks

// One fused kernel, 256 blocks (1/CU). Block = (b, l-group of 8). For each l,
// sim points j in [6l, 6l+6): pcf/pct index l (=j//6), dm indexes (j+5)//6
// (jr==0 -> l, jr>=1 -> l+1). dm in {0,1} multiplies both pcf and kv in the
// reference, so a single output-side factor is exact.
//   out[b,j,o] = sum_k dm * ( sum_h h[jl,k,h]*Q[row,h,o] + Pb[row,o] )
//   row = l+k-4 (ri = il+k in the block's 12-row window)
//   Q[row] = F[row,:] @ W2  (16x32 per row), Pb[row] = F[row,:] @ b2
//   h = relu(te @ W1 + b1), te[2i|2i+1] = sin|cos((times[b,j]-tt[row])*inv[i])
__global__ __launch_bounds__(256) void fused_kernel(
        const float* __restrict__ times, const float* __restrict__ true_times,
        const float* __restrict__ tf,    const int* __restrict__ mask,
        const float* __restrict__ W1,    const float* __restrict__ b1,
        const float* __restrict__ W2,    const float* __restrict__ b2,
        float* __restrict__ out) {
    const int l0  = blockIdx.x * LPB;   // first l of this block
    const int b   = blockIdx.y;
    const int tid = threadIdx.x;

    __shared__ float sQ[NROW][HID * OUTC];      // 12*512*4 = 24.6 KB
    __shared__ float sPb[NROW][OUTC];           // 1.5 KB
    __shared__ float sF[NROW][CCH];             // 1.5 KB
    __shared__ float sW1[CCH * HID];            // 2 KB
    __shared__ float sb1[HID];
    __shared__ float sPT[NROW];                 // true_times per row
    __shared__ float sM[NROW + 1];              // mask rows l0-4 .. l0+LPB
    __shared__ float sT[LPB * 6];               // times for the 48 sim points
    __shared__ float sInv[16];                  // 1/pos per (c>>1)
    __shared__ float sH[NCH * HID];             // 240*16*4 = 15.4 KB

    // ---- phase 1: small loads ----
    for (int e = tid; e < CCH * HID; e += 256) sW1[e] = W1[e];
    for (int e = tid; e < NROW * CCH; e += 256) {   // 384
        int ri = e >> 5, c = e & 31;
        int row = l0 + ri - (KK - 1);
        sF[ri][c] = (row >= 0) ? tf[(size_t)(b * LEN + row) * CCH + c] : 0.f;
    }
    if (tid < HID) sb1[tid] = b1[tid];
    if (tid < 16) sInv[tid] = __powf(10000.f, -(float)tid * (1.f / 16.f));
    if (tid < NROW) {
        int row = l0 + tid - (KK - 1);
        sPT[tid] = (row >= 0) ? true_times[b * LEN + row] : 0.f;
    }
    if (tid >= 32 && tid < 32 + NROW + 1) {
        int i = tid - 32;
        int row = l0 + i - (KK - 1);
        int rc = row < (LEN - 1) ? row : (LEN - 1);   // i==NROW only at l0+LPB==LEN (unused)
        sM[i] = (row >= 0 && mask[b * LEN + rc] != 0) ? 1.f : 0.f;
    }
    if (tid >= 64 && tid < 64 + LPB * 6) {
        int jl = tid - 64;
        int j = 6 * l0 + jl;
        sT[jl] = (j < LALL) ? times[(size_t)b * LALL + j] : 0.f;
    }
    __syncthreads();

    // ---- phase 2a: Q rows (F @ W2), 2 (h,o) columns per thread, 12 rows ----
    {
        int o = tid & 31;
        int h0 = tid >> 5;            // entry tid        -> h = tid>>5
        int h1 = (tid + 256) >> 5;    // entry tid + 256
        const float* w0 = W2 + (size_t)h0 * (CCH * OUTC) + o;
        const float* w1 = W2 + (size_t)h1 * (CCH * OUTC) + o;
        float acc0[NROW], acc1[NROW];
#pragma unroll
        for (int r = 0; r < NROW; ++r) { acc0[r] = 0.f; acc1[r] = 0.f; }
#pragma unroll
        for (int c = 0; c < CCH; ++c) {
            float wv0 = w0[c * OUTC];
            float wv1 = w1[c * OUTC];
#pragma unroll
            for (int r = 0; r < NROW; ++r) {
                float fv = sF[r][c];            // same addr across lanes: broadcast
                acc0[r] += fv * wv0;
                acc1[r] += fv * wv1;
            }
        }
#pragma unroll
        for (int r = 0; r < NROW; ++r) {
            sQ[r][tid]       = acc0[r];
            sQ[r][tid + 256] = acc1[r];
        }
    }
    // ---- phase 2b: Pb rows (F @ b2) ----
    for (int e = tid; e < NROW * OUTC; e += 256) {   // 384
        int ri = e >> 5, o = e & 31;
        float acc = 0.f;
#pragma unroll
        for (int c = 0; c < CCH; ++c) acc += sF[ri][c] * b2[c * OUTC + o];
        sPb[ri][o] = acc;
    }
    // ---- phase 2c: te (regs) + h = relu(te @ W1 + b1), one thread per chunk ----
    if (tid < NCH) {                  // 240 chunks = (jl, k)
        int k  = tid % KK;
        int jl = tid / KK;            // il*6 + jr
        int il = jl / 6;
        float dt = sT[jl] - sPT[il + k];
        float te[CCH];
#pragma unroll
        for (int i = 0; i < 16; ++i) {
            float r = dt * sInv[i];
            __sincosf(r, &te[2 * i], &te[2 * i + 1]);
        }
        float hacc[HID];
#pragma unroll
        for (int hh = 0; hh < HID; ++hh) hacc[hh] = sb1[hh];
#pragma unroll
        for (int c = 0; c < CCH; ++c) {
            float tv = te[c];
#pragma unroll
            for (int hh = 0; hh < HID; ++hh) hacc[hh] += tv * sW1[c * HID + hh];
        }
#pragma unroll
        for (int hh = 0; hh < HID; ++hh)
            sH[tid * HID + hh] = hacc[hh] > 0.f ? hacc[hh] : 0.f;
    }
    __syncthreads();

    // ---- phase 3: outputs (1536 values, 6/thread) ----
    for (int e = tid; e < LPB * 6 * OUTC; e += 256) {
        int o  = e & 31;
        int jr = (e >> 5) % 6;
        int il = e / (6 * OUTC);
        int j = 6 * (l0 + il) + jr;
        if (j < LALL) {
            int sel = jr > 0 ? 1 : 0;
            float mlm = sM[il + sel + (KK - 1)];
            float acc = 0.f;
#pragma unroll
            for (int k = 0; k < KK; ++k) {
                float dmv = sM[il + sel + k] * mlm;
                int ri = il + k;
                const float* hp = &sH[((il * 6 + jr) * KK + k) * HID];
                const float* qp = &sQ[ri][o];
                float a2 = sPb[ri][o];
#pragma unroll
                for (int hh = 0; hh < HID; ++hh) a2 += hp[hh] * qp[hh * OUTC];
                acc += dmv * a2;
            }
            out[((size_t)b * LALL + j) * OUTC + o] = acc;
        }
    }
}

extern "C" void kernel_launch(void* const* d_in, const int* in_sizes, int n_in,
                              void* d_out, int out_size, void* d_ws, size_t ws_size,
                              hipStream_t stream) {
    const float* times      = (const float*)d_in[0];
    const float* true_times = (const float*)d_in[1];
    const float* tf         = (const float*)d_in[2];
    const int*   mask       = (const int*)d_in[3];
    // d_in[4] = sim_size (scalar, =5, baked into constants)
    const float* W1         = (const float*)d_in[5];
    const float* b1         = (const float*)d_in[6];
    const float* W2         = (const float*)d_in[7];
    const float* b2         = (const float*)d_in[8];
    float* out = (float*)d_out;

    fused_kernel<<<dim3(LEN / LPB, BS), 256, 0, stream>>>(
        times, true_times, tf, mask, W1, b1, W2, b2, out);
}